// Round 12
// baseline (204.077 us; speedup 1.0000x reference)
//
#include <hip/hip_runtime.h>
#include <math.h>

typedef unsigned short ush;
typedef unsigned int u32;
typedef short bf16x8 __attribute__((ext_vector_type(8)));
typedef float f32x4 __attribute__((ext_vector_type(4)));
typedef float f32x2 __attribute__((ext_vector_type(2)));
typedef ush ushx8 __attribute__((ext_vector_type(8)));

// ---------- bf16 helpers ----------
__device__ __forceinline__ ush f2bf(float f) {
    unsigned u = __float_as_uint(f);
    u += 0x7FFFu + ((u >> 16) & 1u);
    return (ush)(u >> 16);
}
__device__ __forceinline__ float bf2f(ush u) {
    return __uint_as_float((unsigned)u << 16);
}
__device__ __forceinline__ f32x2 unpack2(u32 w) {
    f32x2 f;
    f.x = __uint_as_float(w << 16);
    f.y = __uint_as_float(w & 0xffff0000u);
    return f;
}

// ---------- pack W into MFMA B-fragment order, hi/lo ----------
__global__ __launch_bounds__(64) void prep_w_k(
    const float* __restrict__ Wl1, const float* __restrict__ Wr1,
    const float* __restrict__ Wl2, const float* __restrict__ Wr2,
    ush* __restrict__ wph, ush* __restrict__ wpl) {
    const int bid = blockIdx.x, l = threadIdx.x;
    const float* W;
    int C, fid;
    if (bid < 32)      { W = Wl1; C = 128; fid = bid; }
    else if (bid < 64) { W = Wr1; C = 128; fid = bid - 32; }
    else if (bid < 80) { W = Wl2; C = 64;  fid = bid - 64; }
    else               { W = Wr2; C = 64;  fid = bid - 80; }
    const int nc16 = C / 16;
    const int ks = fid / nc16, c16 = fid % nc16;
#pragma unroll
    for (int j = 0; j < 8; ++j) {
        const int k = ks * 32 + (l >> 4) * 8 + j;
        const int c = c16 * 16 + (l & 15);
        const float v = W[(size_t)k * C + c];
        const ush h = f2bf(v);
        wph[(size_t)(bid * 64 + l) * 8 + j] = h;
        wpl[(size_t)(bid * 64 + l) * 8 + j] = f2bf(v - bf2f(h));
    }
}

// ---------- layer-1 MFMA GEMM: A = f32 x (hi/lo split in-register) ----------
__global__ __launch_bounds__(256) void gemm1_k(
    const float* __restrict__ x,
    const ush* __restrict__ wh1, const ush* __restrict__ wl1,
    const ush* __restrict__ wh2, const ush* __restrict__ wl2,
    ush* __restrict__ ybf, float* __restrict__ yf, int n) {
    const int l = threadIdx.x & 63;
    const int w = threadIdx.x >> 6;
    const int r0 = blockIdx.x * 64 + w * 16;
    const int arow = min(r0 + (l & 15), n - 1);
    const int kb = (l >> 4) * 8;

    bf16x8 ah[4], al[4];
#pragma unroll
    for (int ks = 0; ks < 4; ++ks) {
        const float* ap = x + (size_t)arow * 128 + ks * 32 + kb;
        const float4 v0 = *reinterpret_cast<const float4*>(ap);
        const float4 v1 = *reinterpret_cast<const float4*>(ap + 4);
        const float fv[8] = {v0.x, v0.y, v0.z, v0.w, v1.x, v1.y, v1.z, v1.w};
#pragma unroll
        for (int j = 0; j < 8; ++j) {
            const ush h = f2bf(fv[j]);
            ah[ks][j] = (short)h;
            al[ks][j] = (short)f2bf(fv[j] - bf2f(h));
        }
    }
    const int drow = (l >> 4) * 4;
    const int dcol = l & 15;
#pragma unroll
    for (int slab = 0; slab < 4; ++slab) {
        const bool isW1 = slab < 2;
        const int sl = slab & 1;
        const ush* __restrict__ wh = isW1 ? wh1 : wh2;
        const ush* __restrict__ wl = isW1 ? wl1 : wl2;
#pragma unroll
        for (int c16 = 0; c16 < 4; ++c16) {
            f32x4 acc = {0.f, 0.f, 0.f, 0.f};
#pragma unroll
            for (int ks = 0; ks < 4; ++ks) {
                const int fid = ks * 8 + sl * 4 + c16;
                const bf16x8 bh = *reinterpret_cast<const bf16x8*>(wh + (size_t)(fid * 64 + l) * 8);
                const bf16x8 bl = *reinterpret_cast<const bf16x8*>(wl + (size_t)(fid * 64 + l) * 8);
                acc = __builtin_amdgcn_mfma_f32_16x16x32_bf16(ah[ks], bh, acc, 0, 0, 0);
                acc = __builtin_amdgcn_mfma_f32_16x16x32_bf16(al[ks], bh, acc, 0, 0, 0);
                acc = __builtin_amdgcn_mfma_f32_16x16x32_bf16(ah[ks], bl, acc, 0, 0, 0);
            }
            const int cg = sl * 64 + c16 * 16 + dcol;
#pragma unroll
            for (int q = 0; q < 4; ++q) {
                const int gr = r0 + drow + q;
                if (gr < n) {
                    if (isW1) ybf[(size_t)gr * 128 + cg] = f2bf(acc[q]);
                    else      yf[(size_t)gr * 128 + cg] = acc[q];
                }
            }
        }
    }
}

// ---------- layer-2 MFMA GEMM: A = bf16 hi/lo pair (h1), C=64 per W ----------
__global__ __launch_bounds__(256) void gemm2_k(
    const ush* __restrict__ ahi, const ush* __restrict__ alo,
    const ush* __restrict__ whl, const ush* __restrict__ wll,
    const ush* __restrict__ whr, const ush* __restrict__ wlr,
    ush* __restrict__ ybf, float* __restrict__ yf, int n) {
    const int l = threadIdx.x & 63;
    const int w = threadIdx.x >> 6;
    const int r0 = blockIdx.x * 64 + w * 16;
    const int arow = min(r0 + (l & 15), n - 1);
    const int kb = (l >> 4) * 8;
    bf16x8 ah[4], al[4];
#pragma unroll
    for (int ks = 0; ks < 4; ++ks) {
        ah[ks] = *reinterpret_cast<const bf16x8*>(ahi + (size_t)arow * 128 + ks * 32 + kb);
        al[ks] = *reinterpret_cast<const bf16x8*>(alo + (size_t)arow * 128 + ks * 32 + kb);
    }
    const int drow = (l >> 4) * 4;
    const int dcol = l & 15;
#pragma unroll
    for (int slab = 0; slab < 2; ++slab) {
        const ush* __restrict__ wh = slab ? whr : whl;
        const ush* __restrict__ wl = slab ? wlr : wll;
#pragma unroll
        for (int c16 = 0; c16 < 4; ++c16) {
            f32x4 acc = {0.f, 0.f, 0.f, 0.f};
#pragma unroll
            for (int ks = 0; ks < 4; ++ks) {
                const int fid = ks * 4 + c16;
                const bf16x8 bh = *reinterpret_cast<const bf16x8*>(wh + (size_t)(fid * 64 + l) * 8);
                const bf16x8 bl = *reinterpret_cast<const bf16x8*>(wl + (size_t)(fid * 64 + l) * 8);
                acc = __builtin_amdgcn_mfma_f32_16x16x32_bf16(ah[ks], bh, acc, 0, 0, 0);
                acc = __builtin_amdgcn_mfma_f32_16x16x32_bf16(al[ks], bh, acc, 0, 0, 0);
                acc = __builtin_amdgcn_mfma_f32_16x16x32_bf16(ah[ks], bl, acc, 0, 0, 0);
            }
            const int cg = c16 * 16 + dcol;
#pragma unroll
            for (int q = 0; q < 4; ++q) {
                const int gr = r0 + drow + q;
                if (gr < n) {
                    if (slab == 0) ybf[(size_t)gr * 64 + cg] = f2bf(acc[q]);
                    else           yf[(size_t)gr * 64 + cg] = acc[q];
                }
            }
        }
    }
}

// ================= CSR build via 2-level counting sort =================
__global__ __launch_bounds__(256) void hist_k(const int* __restrict__ dsts,
                                              int* __restrict__ ghist,
                                              int e0, int etot) {
    __shared__ int h[512];
    const int t = threadIdx.x;
    for (int i = t; i < 512; i += 256) h[i] = 0;
    __syncthreads();
    for (int i = blockIdx.x * blockDim.x + t; i < etot; i += gridDim.x * blockDim.x) {
        const int d = (i < e0) ? dsts[i] : (i - e0);
        atomicAdd(&h[d >> 7], 1);
    }
    __syncthreads();
    for (int i = t; i < 512; i += 256)
        if (h[i]) atomicAdd(&ghist[i], h[i]);
}

__global__ __launch_bounds__(512) void scanb_k(const int* __restrict__ ghist,
                                               int* __restrict__ boff,
                                               int* __restrict__ cur) {
    __shared__ int red[512];
    const int t = threadIdx.x;
    const int x = ghist[t];
    red[t] = x;
    __syncthreads();
#pragma unroll
    for (int s = 1; s < 512; s <<= 1) {
        const int add = (t >= s) ? red[t - s] : 0;
        __syncthreads();
        red[t] += add;
        __syncthreads();
    }
    const int excl = red[t] - x;
    boff[t] = excl;
    cur[t] = excl;
}

// packed pair: src (24 bits) | (dst & 127) << 24
__global__ __launch_bounds__(256) void semisort_k(
    const int* __restrict__ srcs, const int* __restrict__ dsts,
    int* __restrict__ cur, int* __restrict__ pairs, int e0, int etot) {
    __shared__ int hist[512], gbase[512], lcur[512];
    const int t = threadIdx.x;
    const int start = blockIdx.x * 2048;
    const int end = min(start + 2048, etot);
    for (int i = t; i < 512; i += 256) { hist[i] = 0; lcur[i] = 0; }
    __syncthreads();
    for (int i = start + t; i < end; i += 256) {
        const int d = (i < e0) ? dsts[i] : (i - e0);
        atomicAdd(&hist[d >> 7], 1);
    }
    __syncthreads();
    for (int i = t; i < 512; i += 256) {
        const int c = hist[i];
        gbase[i] = c ? atomicAdd(&cur[i], c) : 0;
    }
    __syncthreads();
    for (int i = start + t; i < end; i += 256) {
        int s, d;
        if (i < e0) { s = srcs[i]; d = dsts[i]; } else { s = d = i - e0; }
        const int b = d >> 7;
        const int p = atomicAdd(&lcur[b], 1);
        pairs[gbase[b] + p] = s | ((d & 127) << 24);
    }
}

// one block per bucket: per-dst count -> scan -> row_ptr + csr fill + deg hist
__global__ __launch_bounds__(256) void bucket_fill_k(
    const int* __restrict__ pairs, const int* __restrict__ boff,
    int* __restrict__ row_ptr, int* __restrict__ csr_src,
    int* __restrict__ dbin, int n, int etot) {
    __shared__ int cnt[128], cur[128], hd[128];
    const int b = blockIdx.x, t = threadIdx.x;
    const int lo = boff[b], hi = boff[b + 1];
    if (t < 128) { cnt[t] = 0; hd[t] = 0; }
    __syncthreads();
    for (int e = lo + t; e < hi; e += 256)
        atomicAdd(&cnt[(pairs[e] >> 24) & 127], 1);
    __syncthreads();
    const int x = (t < 128) ? cnt[t] : 0;
#pragma unroll
    for (int s = 1; s < 128; s <<= 1) {
        const int add = (t < 128 && t >= s) ? cnt[t - s] : 0;
        __syncthreads();
        if (t < 128) cnt[t] += add;
        __syncthreads();
    }
    if (t < 128) {
        const int excl = cnt[t] - x;
        cur[t] = excl;
        const int d = b * 128 + t;
        if (d < n) {
            row_ptr[d] = lo + excl;
            atomicAdd(&hd[127 - min(x, 127)], 1);
        }
    }
    if (b == 0 && t == 0) row_ptr[n] = etot;
    __syncthreads();
    if (t < 128 && hd[t]) atomicAdd(&dbin[t], hd[t]);
    for (int e = lo + t; e < hi; e += 256) {
        const int p = pairs[e];
        const int pos = atomicAdd(&cur[(p >> 24) & 127], 1);
        csr_src[lo + pos] = p & 0xFFFFFF;
    }
}

__global__ __launch_bounds__(128) void deg_scan_k(const int* __restrict__ dbin,
                                                  int* __restrict__ dcur) {
    __shared__ int red[128];
    const int t = threadIdx.x;
    const int x = dbin[t];
    red[t] = x;
    __syncthreads();
#pragma unroll
    for (int s = 1; s < 128; s <<= 1) {
        const int add = (t >= s) ? red[t - s] : 0;
        __syncthreads();
        red[t] += add;
        __syncthreads();
    }
    dcur[t] = red[t] - x;
}

__global__ __launch_bounds__(256) void deg_scatter_k(const int* __restrict__ row_ptr,
                                                     int* __restrict__ dcur,
                                                     int* __restrict__ order, int n) {
    __shared__ int h[128], gbase[128], lcur[128];
    const int t = threadIdx.x;
    if (t < 128) { h[t] = 0; lcur[t] = 0; }
    __syncthreads();
    const int d = blockIdx.x * 256 + t;
    int bin = -1;
    if (d < n) {
        const int deg = row_ptr[d + 1] - row_ptr[d];
        bin = 127 - min(deg, 127);
        atomicAdd(&h[bin], 1);
    }
    __syncthreads();
    if (t < 128) gbase[t] = h[t] ? atomicAdd(&dcur[t], h[t]) : 0;
    __syncthreads();
    if (d < n) {
        const int p = atomicAdd(&lcur[bin], 1);
        order[gbase[bin] + p] = d;
    }
}

// ---------- fused per-dst softmax aggregation, H=2 (128 cols, xl bf16) ----------
// one wave per dst; 4 groups x 16 lanes; packed-f32 (v_pk_*) inner math.
__global__ __launch_bounds__(256) void gat_dst2_k(
    const ush* __restrict__ xl, const float* __restrict__ xr,
    const int* __restrict__ row_ptr, const int* __restrict__ csr_src,
    const int* __restrict__ order, const float* __restrict__ att,
    const float* __restrict__ bias, ush* __restrict__ h1hi,
    ush* __restrict__ h1lo, int n) {
    const int lane = threadIdx.x & 63;
    const int g = lane >> 4, il = lane & 15;
    const int w = (blockIdx.x * blockDim.x + threadIdx.x) >> 6;
    if (w >= n) return;
    const int d = order[w];
    const f32x2 c02 = {0.2f, 0.2f};

    f32x2 xv2[4], at2[4];
    {
        const float4* xp = reinterpret_cast<const float4*>(xr + (size_t)d * 128 + il * 8);
        const float4* ap = reinterpret_cast<const float4*>(att + il * 8);
        const float4 x0 = xp[0], x1 = xp[1], a0 = ap[0], a1 = ap[1];
        xv2[0] = {x0.x, x0.y}; xv2[1] = {x0.z, x0.w};
        xv2[2] = {x1.x, x1.y}; xv2[3] = {x1.z, x1.w};
        at2[0] = {a0.x, a0.y}; at2[1] = {a0.z, a0.w};
        at2[2] = {a1.x, a1.y}; at2[3] = {a1.z, a1.w};
    }
    const int rp0 = row_ptr[d], rp1 = row_ptr[d + 1];

    float s = 0.f;
    f32x2 acc2[4] = {{0.f, 0.f}, {0.f, 0.f}, {0.f, 0.f}, {0.f, 0.f}};
    int i = rp0 + g;
    for (; i + 4 < rp1; i += 8) {
        const int s0 = csr_src[i];
        const int s1 = csr_src[i + 4];
        const uint4 q0 = *reinterpret_cast<const uint4*>(xl + (((size_t)(unsigned)s0) << 7) + il * 8);
        const uint4 q1 = *reinterpret_cast<const uint4*>(xl + (((size_t)(unsigned)s1) << 7) + il * 8);
        f32x2 f0[4], f1[4];
        f0[0] = unpack2(q0.x); f0[1] = unpack2(q0.y); f0[2] = unpack2(q0.z); f0[3] = unpack2(q0.w);
        f1[0] = unpack2(q1.x); f1[1] = unpack2(q1.y); f1[2] = unpack2(q1.z); f1[3] = unpack2(q1.w);
        f32x2 p20 = {0.f, 0.f}, p21 = {0.f, 0.f};
#pragma unroll
        for (int p = 0; p < 4; ++p) {
            const f32x2 v0 = f0[p] + xv2[p];
            const f32x2 v1 = f1[p] + xv2[p];
            p20 = __builtin_elementwise_fma(at2[p], __builtin_elementwise_max(v0, v0 * c02), p20);
            p21 = __builtin_elementwise_fma(at2[p], __builtin_elementwise_max(v1, v1 * c02), p21);
        }
        float p0 = p20.x + p20.y, p1 = p21.x + p21.y;
        p0 += __shfl_xor(p0, 4, 64); p0 += __shfl_xor(p0, 2, 64); p0 += __shfl_xor(p0, 1, 64);
        p1 += __shfl_xor(p1, 4, 64); p1 += __shfl_xor(p1, 2, 64); p1 += __shfl_xor(p1, 1, 64);
        const float w0 = __expf(p0), w1 = __expf(p1);
        s += w0 + w1;
        const f32x2 w20 = {w0, w0}, w21 = {w1, w1};
#pragma unroll
        for (int p = 0; p < 4; ++p)
            acc2[p] = __builtin_elementwise_fma(w20, f0[p],
                      __builtin_elementwise_fma(w21, f1[p], acc2[p]));
    }
    if (i < rp1) {
        const int s0 = csr_src[i];
        const uint4 q0 = *reinterpret_cast<const uint4*>(xl + (((size_t)(unsigned)s0) << 7) + il * 8);
        f32x2 f0[4];
        f0[0] = unpack2(q0.x); f0[1] = unpack2(q0.y); f0[2] = unpack2(q0.z); f0[3] = unpack2(q0.w);
        f32x2 p20 = {0.f, 0.f};
#pragma unroll
        for (int p = 0; p < 4; ++p) {
            const f32x2 v0 = f0[p] + xv2[p];
            p20 = __builtin_elementwise_fma(at2[p], __builtin_elementwise_max(v0, v0 * c02), p20);
        }
        float p0 = p20.x + p20.y;
        p0 += __shfl_xor(p0, 4, 64); p0 += __shfl_xor(p0, 2, 64); p0 += __shfl_xor(p0, 1, 64);
        const float w0 = __expf(p0);
        s += w0;
        const f32x2 w20 = {w0, w0};
#pragma unroll
        for (int p = 0; p < 4; ++p)
            acc2[p] = __builtin_elementwise_fma(w20, f0[p], acc2[p]);
    }
#pragma unroll
    for (int off = 16; off <= 32; off <<= 1) {
        s += __shfl_xor(s, off, 64);
#pragma unroll
        for (int p = 0; p < 4; ++p) {
            acc2[p].x += __shfl_xor(acc2[p].x, off, 64);
            acc2[p].y += __shfl_xor(acc2[p].y, off, 64);
        }
    }
    if (g == 0) {
        const float inv = 1.f / (s + 1e-16f);
        float bv[8];
        {
            const float4* bp = reinterpret_cast<const float4*>(bias + il * 8);
            const float4 b0 = bp[0], b1 = bp[1];
            bv[0]=b0.x; bv[1]=b0.y; bv[2]=b0.z; bv[3]=b0.w;
            bv[4]=b1.x; bv[5]=b1.y; bv[6]=b1.z; bv[7]=b1.w;
        }
        ushx8 hh, ll;
#pragma unroll
        for (int p = 0; p < 4; ++p) {
            const float o0 = fmaxf(fmaf(acc2[p].x, inv, bv[2 * p]), 0.f);
            const float o1 = fmaxf(fmaf(acc2[p].y, inv, bv[2 * p + 1]), 0.f);
            const ush h0 = f2bf(o0), h1 = f2bf(o1);
            hh[2 * p] = h0;     ll[2 * p] = f2bf(o0 - bf2f(h0));
            hh[2 * p + 1] = h1; ll[2 * p + 1] = f2bf(o1 - bf2f(h1));
        }
        *reinterpret_cast<ushx8*>(h1hi + (size_t)d * 128 + il * 8) = hh;
        *reinterpret_cast<ushx8*>(h1lo + (size_t)d * 128 + il * 8) = ll;
    }
}

// ---------- fused per-dst softmax aggregation, H=1 (64 cols, xl bf16) ----------
// one wave per dst; 8 groups x 8 lanes; packed-f32 inner math.
__global__ __launch_bounds__(256) void gat_dst1_k(
    const ush* __restrict__ xl, const float* __restrict__ xr,
    const int* __restrict__ row_ptr, const int* __restrict__ csr_src,
    const int* __restrict__ order, const float* __restrict__ att,
    const float* __restrict__ bias, float* __restrict__ out, int n) {
    const int lane = threadIdx.x & 63;
    const int g = lane >> 3, il = lane & 7;
    const int w = (blockIdx.x * blockDim.x + threadIdx.x) >> 6;
    if (w >= n) return;
    const int d = order[w];
    const f32x2 c02 = {0.2f, 0.2f};

    f32x2 xv2[4], at2[4];
    {
        const float4* xp = reinterpret_cast<const float4*>(xr + (size_t)d * 64 + il * 8);
        const float4* ap = reinterpret_cast<const float4*>(att + il * 8);
        const float4 x0 = xp[0], x1 = xp[1], a0 = ap[0], a1 = ap[1];
        xv2[0] = {x0.x, x0.y}; xv2[1] = {x0.z, x0.w};
        xv2[2] = {x1.x, x1.y}; xv2[3] = {x1.z, x1.w};
        at2[0] = {a0.x, a0.y}; at2[1] = {a0.z, a0.w};
        at2[2] = {a1.x, a1.y}; at2[3] = {a1.z, a1.w};
    }
    const int rp0 = row_ptr[d], rp1 = row_ptr[d + 1];

    float s = 0.f;
    f32x2 acc2[4] = {{0.f, 0.f}, {0.f, 0.f}, {0.f, 0.f}, {0.f, 0.f}};
    int i = rp0 + g;
    for (; i + 8 < rp1; i += 16) {
        const int s0 = csr_src[i];
        const int s1 = csr_src[i + 8];
        const uint4 q0 = *reinterpret_cast<const uint4*>(xl + (((size_t)(unsigned)s0) << 6) + il * 8);
        const uint4 q1 = *reinterpret_cast<const uint4*>(xl + (((size_t)(unsigned)s1) << 6) + il * 8);
        f32x2 f0[4], f1[4];
        f0[0] = unpack2(q0.x); f0[1] = unpack2(q0.y); f0[2] = unpack2(q0.z); f0[3] = unpack2(q0.w);
        f1[0] = unpack2(q1.x); f1[1] = unpack2(q1.y); f1[2] = unpack2(q1.z); f1[3] = unpack2(q1.w);
        f32x2 p20 = {0.f, 0.f}, p21 = {0.f, 0.f};
#pragma unroll
        for (int p = 0; p < 4; ++p) {
            const f32x2 v0 = f0[p] + xv2[p];
            const f32x2 v1 = f1[p] + xv2[p];
            p20 = __builtin_elementwise_fma(at2[p], __builtin_elementwise_max(v0, v0 * c02), p20);
            p21 = __builtin_elementwise_fma(at2[p], __builtin_elementwise_max(v1, v1 * c02), p21);
        }
        float p0 = p20.x + p20.y, p1 = p21.x + p21.y;
        p0 += __shfl_xor(p0, 4, 64); p0 += __shfl_xor(p0, 2, 64); p0 += __shfl_xor(p0, 1, 64);
        p1 += __shfl_xor(p1, 4, 64); p1 += __shfl_xor(p1, 2, 64); p1 += __shfl_xor(p1, 1, 64);
        const float w0 = __expf(p0), w1 = __expf(p1);
        s += w0 + w1;
        const f32x2 w20 = {w0, w0}, w21 = {w1, w1};
#pragma unroll
        for (int p = 0; p < 4; ++p)
            acc2[p] = __builtin_elementwise_fma(w20, f0[p],
                      __builtin_elementwise_fma(w21, f1[p], acc2[p]));
    }
    if (i < rp1) {
        const int s0 = csr_src[i];
        const uint4 q0 = *reinterpret_cast<const uint4*>(xl + (((size_t)(unsigned)s0) << 6) + il * 8);
        f32x2 f0[4];
        f0[0] = unpack2(q0.x); f0[1] = unpack2(q0.y); f0[2] = unpack2(q0.z); f0[3] = unpack2(q0.w);
        f32x2 p20 = {0.f, 0.f};
#pragma unroll
        for (int p = 0; p < 4; ++p) {
            const f32x2 v0 = f0[p] + xv2[p];
            p20 = __builtin_elementwise_fma(at2[p], __builtin_elementwise_max(v0, v0 * c02), p20);
        }
        float p0 = p20.x + p20.y;
        p0 += __shfl_xor(p0, 4, 64); p0 += __shfl_xor(p0, 2, 64); p0 += __shfl_xor(p0, 1, 64);
        const float w0 = __expf(p0);
        s += w0;
        const f32x2 w20 = {w0, w0};
#pragma unroll
        for (int p = 0; p < 4; ++p)
            acc2[p] = __builtin_elementwise_fma(w20, f0[p], acc2[p]);
    }
#pragma unroll
    for (int off = 8; off <= 32; off <<= 1) {
        s += __shfl_xor(s, off, 64);
#pragma unroll
        for (int p = 0; p < 4; ++p) {
            acc2[p].x += __shfl_xor(acc2[p].x, off, 64);
            acc2[p].y += __shfl_xor(acc2[p].y, off, 64);
        }
    }
    if (g == 0) {
        const float inv = 1.f / (s + 1e-16f);
        float bv[8];
        {
            const float4* bp = reinterpret_cast<const float4*>(bias + il * 8);
            const float4 b0 = bp[0], b1 = bp[1];
            bv[0]=b0.x; bv[1]=b0.y; bv[2]=b0.z; bv[3]=b0.w;
            bv[4]=b1.x; bv[5]=b1.y; bv[6]=b1.z; bv[7]=b1.w;
        }
        float4 o0, o1;
        o0.x = fmaxf(fmaf(acc2[0].x, inv, bv[0]), 0.f);
        o0.y = fmaxf(fmaf(acc2[0].y, inv, bv[1]), 0.f);
        o0.z = fmaxf(fmaf(acc2[1].x, inv, bv[2]), 0.f);
        o0.w = fmaxf(fmaf(acc2[1].y, inv, bv[3]), 0.f);
        o1.x = fmaxf(fmaf(acc2[2].x, inv, bv[4]), 0.f);
        o1.y = fmaxf(fmaf(acc2[2].y, inv, bv[5]), 0.f);
        o1.z = fmaxf(fmaf(acc2[3].x, inv, bv[6]), 0.f);
        o1.w = fmaxf(fmaf(acc2[3].y, inv, bv[7]), 0.f);
        float4* op = reinterpret_cast<float4*>(out + (size_t)d * 64 + il * 8);
        op[0] = o0;
        op[1] = o1;
    }
}

extern "C" void kernel_launch(void* const* d_in, const int* in_sizes, int n_in,
                              void* d_out, int out_size, void* d_ws, size_t ws_size,
                              hipStream_t stream) {
    const float* x    = (const float*)d_in[0];
    const int*   ei   = (const int*)d_in[1];
    const float* Wl1  = (const float*)d_in[2];
    const float* Wr1  = (const float*)d_in[3];
    const float* att1 = (const float*)d_in[4];
    const float* b1   = (const float*)d_in[5];
    const float* Wl2  = (const float*)d_in[6];
    const float* Wr2  = (const float*)d_in[7];
    const float* att2 = (const float*)d_in[8];
    const float* b2   = (const float*)d_in[9];

    const int n    = in_sizes[0] / 128;   // 50000
    const int e0   = in_sizes[1] / 2;     // 800000
    const int etot = e0 + n;
    const int* srcs = ei;
    const int* dsts = ei + e0;

    float* ws = (float*)d_ws;
    ush*   h1hi = (ush*)ws;                        // n*128 ush
    ush*   h1lo = (ush*)(ws + (size_t)n * 64);     // n*128 ush
    ush*   xlbf = (ush*)(ws + (size_t)n * 128);    // n*128 ush
    float* xr   = ws + (size_t)n * 192;            // n*128 f32
    int* row_ptr = (int*)(ws + (size_t)n * 320);   // n+2
    int* ghist   = row_ptr + (n + 2);              // 512
    int* dbin    = ghist + 512;                    // 128
    int* dcur    = dbin + 128;                     // 128
    int* boff    = dcur + 128;                     // 512
    int* cur     = boff + 512;                     // 512
    int* order   = cur + 512;                      // n
    int* csr_src = order + n;                      // etot
    int* pairs   = csr_src + etot;                 // etot (packed)
    ush* wph     = (ush*)(pairs + etot);           // 96*512 ush
    ush* wpl     = wph + 96 * 512;                 // 96*512 ush

    const int NB  = (n + 127) / 128;               // 391 <= 512
    const int NDB = (n + 255) / 256;               // 196
    const int nblka = (etot + 2047) / 2048;

    // ---- CSR build via 2-level counting sort (+ fused degree hist) ----
    hipMemsetAsync(ghist, 0, 640 * sizeof(int), stream);  // ghist + dbin
    hist_k<<<256, 256, 0, stream>>>(dsts, ghist, e0, etot);
    scanb_k<<<1, 512, 0, stream>>>(ghist, boff, cur);
    semisort_k<<<nblka, 256, 0, stream>>>(srcs, dsts, cur, pairs, e0, etot);
    bucket_fill_k<<<NB, 256, 0, stream>>>(pairs, boff, row_ptr, csr_src, dbin, n, etot);
    deg_scan_k<<<1, 128, 0, stream>>>(dbin, dcur);
    deg_scatter_k<<<NDB, 256, 0, stream>>>(row_ptr, dcur, order, n);

    // ---- weight prep ----
    prep_w_k<<<96, 64, 0, stream>>>(Wl1, Wr1, Wl2, Wr2, wph, wpl);

    const int gx = (n + 63) / 64;

    // ---- layer 1 (H=2): xl bf16 [n,128], xr f32 [n,128] ----
    gemm1_k<<<gx, 256, 0, stream>>>(x, wph, wpl, wph + 32 * 512, wpl + 32 * 512,
                                    xlbf, xr, n);
    gat_dst2_k<<<(n + 3) / 4, 256, 0, stream>>>(xlbf, xr, row_ptr, csr_src, order,
                                                att1, b1, h1hi, h1lo, n);

    // ---- layer 2 (H=1): xl2 bf16 [n,64], xr2 f32 [n,64] ----
    gemm2_k<<<gx, 256, 0, stream>>>(h1hi, h1lo, wph + 64 * 512, wpl + 64 * 512,
                                    wph + 80 * 512, wpl + 80 * 512, xlbf, xr, n);
    gat_dst1_k<<<(n + 3) / 4, 256, 0, stream>>>(xlbf, xr, row_ptr, csr_src, order,
                                                att2, b2, (float*)d_out, n);
}

// Round 13
// 187.852 us; speedup vs baseline: 1.0864x; 1.0864x over previous
//
#include <hip/hip_runtime.h>
#include <math.h>

typedef unsigned short ush;
typedef short bf16x8 __attribute__((ext_vector_type(8)));
typedef float f32x4 __attribute__((ext_vector_type(4)));
typedef ush ushx8 __attribute__((ext_vector_type(8)));

// ---------- bf16 helpers ----------
__device__ __forceinline__ ush f2bf(float f) {
    unsigned u = __float_as_uint(f);
    u += 0x7FFFu + ((u >> 16) & 1u);
    return (ush)(u >> 16);
}
__device__ __forceinline__ float bf2f(ush u) {
    return __uint_as_float((unsigned)u << 16);
}

// ---------- pack W into MFMA B-fragment order, hi/lo ----------
__global__ __launch_bounds__(64) void prep_w_k(
    const float* __restrict__ Wl1, const float* __restrict__ Wr1,
    const float* __restrict__ Wl2, const float* __restrict__ Wr2,
    ush* __restrict__ wph, ush* __restrict__ wpl) {
    const int bid = blockIdx.x, l = threadIdx.x;
    const float* W;
    int C, fid;
    if (bid < 32)      { W = Wl1; C = 128; fid = bid; }
    else if (bid < 64) { W = Wr1; C = 128; fid = bid - 32; }
    else if (bid < 80) { W = Wl2; C = 64;  fid = bid - 64; }
    else               { W = Wr2; C = 64;  fid = bid - 80; }
    const int nc16 = C / 16;
    const int ks = fid / nc16, c16 = fid % nc16;
#pragma unroll
    for (int j = 0; j < 8; ++j) {
        const int k = ks * 32 + (l >> 4) * 8 + j;
        const int c = c16 * 16 + (l & 15);
        const float v = W[(size_t)k * C + c];
        const ush h = f2bf(v);
        wph[(size_t)(bid * 64 + l) * 8 + j] = h;
        wpl[(size_t)(bid * 64 + l) * 8 + j] = f2bf(v - bf2f(h));
    }
}

// ---------- layer-1 MFMA GEMM: A = f32 x (hi/lo split in-register) ----------
__global__ __launch_bounds__(256) void gemm1_k(
    const float* __restrict__ x,
    const ush* __restrict__ wh1, const ush* __restrict__ wl1,
    const ush* __restrict__ wh2, const ush* __restrict__ wl2,
    ush* __restrict__ ybf, float* __restrict__ yf, int n) {
    const int l = threadIdx.x & 63;
    const int w = threadIdx.x >> 6;
    const int r0 = blockIdx.x * 64 + w * 16;
    const int arow = min(r0 + (l & 15), n - 1);
    const int kb = (l >> 4) * 8;

    bf16x8 ah[4], al[4];
#pragma unroll
    for (int ks = 0; ks < 4; ++ks) {
        const float* ap = x + (size_t)arow * 128 + ks * 32 + kb;
        const float4 v0 = *reinterpret_cast<const float4*>(ap);
        const float4 v1 = *reinterpret_cast<const float4*>(ap + 4);
        const float fv[8] = {v0.x, v0.y, v0.z, v0.w, v1.x, v1.y, v1.z, v1.w};
#pragma unroll
        for (int j = 0; j < 8; ++j) {
            const ush h = f2bf(fv[j]);
            ah[ks][j] = (short)h;
            al[ks][j] = (short)f2bf(fv[j] - bf2f(h));
        }
    }
    const int drow = (l >> 4) * 4;
    const int dcol = l & 15;
#pragma unroll
    for (int slab = 0; slab < 4; ++slab) {
        const bool isW1 = slab < 2;
        const int sl = slab & 1;
        const ush* __restrict__ wh = isW1 ? wh1 : wh2;
        const ush* __restrict__ wl = isW1 ? wl1 : wl2;
#pragma unroll
        for (int c16 = 0; c16 < 4; ++c16) {
            f32x4 acc = {0.f, 0.f, 0.f, 0.f};
#pragma unroll
            for (int ks = 0; ks < 4; ++ks) {
                const int fid = ks * 8 + sl * 4 + c16;
                const bf16x8 bh = *reinterpret_cast<const bf16x8*>(wh + (size_t)(fid * 64 + l) * 8);
                const bf16x8 bl = *reinterpret_cast<const bf16x8*>(wl + (size_t)(fid * 64 + l) * 8);
                acc = __builtin_amdgcn_mfma_f32_16x16x32_bf16(ah[ks], bh, acc, 0, 0, 0);
                acc = __builtin_amdgcn_mfma_f32_16x16x32_bf16(al[ks], bh, acc, 0, 0, 0);
                acc = __builtin_amdgcn_mfma_f32_16x16x32_bf16(ah[ks], bl, acc, 0, 0, 0);
            }
            const int cg = sl * 64 + c16 * 16 + dcol;
#pragma unroll
            for (int q = 0; q < 4; ++q) {
                const int gr = r0 + drow + q;
                if (gr < n) {
                    if (isW1) ybf[(size_t)gr * 128 + cg] = f2bf(acc[q]);
                    else      yf[(size_t)gr * 128 + cg] = acc[q];
                }
            }
        }
    }
}

// ---------- layer-2 MFMA GEMM: A = bf16 hi/lo pair (h1), C=64 per W ----------
__global__ __launch_bounds__(256) void gemm2_k(
    const ush* __restrict__ ahi, const ush* __restrict__ alo,
    const ush* __restrict__ whl, const ush* __restrict__ wll,
    const ush* __restrict__ whr, const ush* __restrict__ wlr,
    ush* __restrict__ ybf, float* __restrict__ yf, int n) {
    const int l = threadIdx.x & 63;
    const int w = threadIdx.x >> 6;
    const int r0 = blockIdx.x * 64 + w * 16;
    const int arow = min(r0 + (l & 15), n - 1);
    const int kb = (l >> 4) * 8;
    bf16x8 ah[4], al[4];
#pragma unroll
    for (int ks = 0; ks < 4; ++ks) {
        ah[ks] = *reinterpret_cast<const bf16x8*>(ahi + (size_t)arow * 128 + ks * 32 + kb);
        al[ks] = *reinterpret_cast<const bf16x8*>(alo + (size_t)arow * 128 + ks * 32 + kb);
    }
    const int drow = (l >> 4) * 4;
    const int dcol = l & 15;
#pragma unroll
    for (int slab = 0; slab < 2; ++slab) {
        const ush* __restrict__ wh = slab ? whr : whl;
        const ush* __restrict__ wl = slab ? wlr : wll;
#pragma unroll
        for (int c16 = 0; c16 < 4; ++c16) {
            f32x4 acc = {0.f, 0.f, 0.f, 0.f};
#pragma unroll
            for (int ks = 0; ks < 4; ++ks) {
                const int fid = ks * 4 + c16;
                const bf16x8 bh = *reinterpret_cast<const bf16x8*>(wh + (size_t)(fid * 64 + l) * 8);
                const bf16x8 bl = *reinterpret_cast<const bf16x8*>(wl + (size_t)(fid * 64 + l) * 8);
                acc = __builtin_amdgcn_mfma_f32_16x16x32_bf16(ah[ks], bh, acc, 0, 0, 0);
                acc = __builtin_amdgcn_mfma_f32_16x16x32_bf16(al[ks], bh, acc, 0, 0, 0);
                acc = __builtin_amdgcn_mfma_f32_16x16x32_bf16(ah[ks], bl, acc, 0, 0, 0);
            }
            const int cg = c16 * 16 + dcol;
#pragma unroll
            for (int q = 0; q < 4; ++q) {
                const int gr = r0 + drow + q;
                if (gr < n) {
                    if (slab == 0) ybf[(size_t)gr * 64 + cg] = f2bf(acc[q]);
                    else           yf[(size_t)gr * 64 + cg] = acc[q];
                }
            }
        }
    }
}

// ================= CSR build via 2-level counting sort =================
__global__ __launch_bounds__(256) void hist_k(const int* __restrict__ dsts,
                                              int* __restrict__ ghist,
                                              int e0, int etot) {
    __shared__ int h[512];
    const int t = threadIdx.x;
    for (int i = t; i < 512; i += 256) h[i] = 0;
    __syncthreads();
    for (int i = blockIdx.x * blockDim.x + t; i < etot; i += gridDim.x * blockDim.x) {
        const int d = (i < e0) ? dsts[i] : (i - e0);
        atomicAdd(&h[d >> 7], 1);
    }
    __syncthreads();
    for (int i = t; i < 512; i += 256)
        if (h[i]) atomicAdd(&ghist[i], h[i]);
}

__global__ __launch_bounds__(512) void scanb_k(const int* __restrict__ ghist,
                                               int* __restrict__ boff,
                                               int* __restrict__ cur) {
    __shared__ int red[512];
    const int t = threadIdx.x;
    const int x = ghist[t];
    red[t] = x;
    __syncthreads();
#pragma unroll
    for (int s = 1; s < 512; s <<= 1) {
        const int add = (t >= s) ? red[t - s] : 0;
        __syncthreads();
        red[t] += add;
        __syncthreads();
    }
    const int excl = red[t] - x;
    boff[t] = excl;
    cur[t] = excl;
}

// packed pair: src (24 bits) | (dst & 127) << 24
__global__ __launch_bounds__(256) void semisort_k(
    const int* __restrict__ srcs, const int* __restrict__ dsts,
    int* __restrict__ cur, int* __restrict__ pairs, int e0, int etot) {
    __shared__ int hist[512], gbase[512], lcur[512];
    const int t = threadIdx.x;
    const int start = blockIdx.x * 2048;
    const int end = min(start + 2048, etot);
    for (int i = t; i < 512; i += 256) { hist[i] = 0; lcur[i] = 0; }
    __syncthreads();
    for (int i = start + t; i < end; i += 256) {
        const int d = (i < e0) ? dsts[i] : (i - e0);
        atomicAdd(&hist[d >> 7], 1);
    }
    __syncthreads();
    for (int i = t; i < 512; i += 256) {
        const int c = hist[i];
        gbase[i] = c ? atomicAdd(&cur[i], c) : 0;
    }
    __syncthreads();
    for (int i = start + t; i < end; i += 256) {
        int s, d;
        if (i < e0) { s = srcs[i]; d = dsts[i]; } else { s = d = i - e0; }
        const int b = d >> 7;
        const int p = atomicAdd(&lcur[b], 1);
        pairs[gbase[b] + p] = s | ((d & 127) << 24);
    }
}

// one block per bucket: per-dst count -> scan -> row_ptr + csr fill + deg hist
__global__ __launch_bounds__(256) void bucket_fill_k(
    const int* __restrict__ pairs, const int* __restrict__ boff,
    int* __restrict__ row_ptr, int* __restrict__ csr_src,
    int* __restrict__ dbin, int n, int etot) {
    __shared__ int cnt[128], cur[128], hd[128];
    const int b = blockIdx.x, t = threadIdx.x;
    const int lo = boff[b], hi = boff[b + 1];
    if (t < 128) { cnt[t] = 0; hd[t] = 0; }
    __syncthreads();
    for (int e = lo + t; e < hi; e += 256)
        atomicAdd(&cnt[(pairs[e] >> 24) & 127], 1);
    __syncthreads();
    const int x = (t < 128) ? cnt[t] : 0;
#pragma unroll
    for (int s = 1; s < 128; s <<= 1) {
        const int add = (t < 128 && t >= s) ? cnt[t - s] : 0;
        __syncthreads();
        if (t < 128) cnt[t] += add;
        __syncthreads();
    }
    if (t < 128) {
        const int excl = cnt[t] - x;
        cur[t] = excl;
        const int d = b * 128 + t;
        if (d < n) {
            row_ptr[d] = lo + excl;
            atomicAdd(&hd[127 - min(x, 127)], 1);
        }
    }
    if (b == 0 && t == 0) row_ptr[n] = etot;
    __syncthreads();
    if (t < 128 && hd[t]) atomicAdd(&dbin[t], hd[t]);
    for (int e = lo + t; e < hi; e += 256) {
        const int p = pairs[e];
        const int pos = atomicAdd(&cur[(p >> 24) & 127], 1);
        csr_src[lo + pos] = p & 0xFFFFFF;
    }
}

__global__ __launch_bounds__(128) void deg_scan_k(const int* __restrict__ dbin,
                                                  int* __restrict__ dcur) {
    __shared__ int red[128];
    const int t = threadIdx.x;
    const int x = dbin[t];
    red[t] = x;
    __syncthreads();
#pragma unroll
    for (int s = 1; s < 128; s <<= 1) {
        const int add = (t >= s) ? red[t - s] : 0;
        __syncthreads();
        red[t] += add;
        __syncthreads();
    }
    dcur[t] = red[t] - x;
}

__global__ __launch_bounds__(256) void deg_scatter_k(const int* __restrict__ row_ptr,
                                                     int* __restrict__ dcur,
                                                     int* __restrict__ order, int n) {
    __shared__ int h[128], gbase[128], lcur[128];
    const int t = threadIdx.x;
    if (t < 128) { h[t] = 0; lcur[t] = 0; }
    __syncthreads();
    const int d = blockIdx.x * 256 + t;
    int bin = -1;
    if (d < n) {
        const int deg = row_ptr[d + 1] - row_ptr[d];
        bin = 127 - min(deg, 127);
        atomicAdd(&h[bin], 1);
    }
    __syncthreads();
    if (t < 128) gbase[t] = h[t] ? atomicAdd(&dcur[t], h[t]) : 0;
    __syncthreads();
    if (d < n) {
        const int p = atomicAdd(&lcur[bin], 1);
        order[gbase[bin] + p] = d;
    }
}

// ---------- fused per-dst softmax aggregation, H=2 (128 cols, xl bf16) ----------
// one wave per dst; 4 groups x 16 lanes x ushort8; scalar math (occupancy-friendly).
__global__ __launch_bounds__(256) void gat_dst2_k(
    const ush* __restrict__ xl, const float* __restrict__ xr,
    const int* __restrict__ row_ptr, const int* __restrict__ csr_src,
    const int* __restrict__ order, const float* __restrict__ att,
    const float* __restrict__ bias, ush* __restrict__ h1hi,
    ush* __restrict__ h1lo, int n) {
    const int lane = threadIdx.x & 63;
    const int g = lane >> 4, il = lane & 15;
    const int w = (blockIdx.x * blockDim.x + threadIdx.x) >> 6;
    if (w >= n) return;
    const int d = order[w];

    float xv[8], av[8];
    {
        const float4* xp = reinterpret_cast<const float4*>(xr + (size_t)d * 128 + il * 8);
        const float4* ap = reinterpret_cast<const float4*>(att + il * 8);
        const float4 x0 = xp[0], x1 = xp[1], a0 = ap[0], a1 = ap[1];
        xv[0]=x0.x; xv[1]=x0.y; xv[2]=x0.z; xv[3]=x0.w;
        xv[4]=x1.x; xv[5]=x1.y; xv[6]=x1.z; xv[7]=x1.w;
        av[0]=a0.x; av[1]=a0.y; av[2]=a0.z; av[3]=a0.w;
        av[4]=a1.x; av[5]=a1.y; av[6]=a1.z; av[7]=a1.w;
    }
    const int rp0 = row_ptr[d], rp1 = row_ptr[d + 1];

    float s = 0.f;
    float acc[8] = {0.f, 0.f, 0.f, 0.f, 0.f, 0.f, 0.f, 0.f};
    int i = rp0 + g;
    for (; i + 4 < rp1; i += 8) {
        const int s0 = csr_src[i];
        const int s1 = csr_src[i + 4];
        const ushx8 u0 = *reinterpret_cast<const ushx8*>(xl + (((size_t)(unsigned)s0) << 7) + il * 8);
        const ushx8 u1 = *reinterpret_cast<const ushx8*>(xl + (((size_t)(unsigned)s1) << 7) + il * 8);
        float f0[8], f1[8], p0 = 0.f, p1 = 0.f;
#pragma unroll
        for (int j = 0; j < 8; ++j) {
            f0[j] = bf2f((ush)u0[j]);
            const float v = f0[j] + xv[j];
            p0 = fmaf(av[j], fmaxf(v, 0.2f * v), p0);
        }
#pragma unroll
        for (int j = 0; j < 8; ++j) {
            f1[j] = bf2f((ush)u1[j]);
            const float v = f1[j] + xv[j];
            p1 = fmaf(av[j], fmaxf(v, 0.2f * v), p1);
        }
        p0 += __shfl_xor(p0, 4, 64); p0 += __shfl_xor(p0, 2, 64); p0 += __shfl_xor(p0, 1, 64);
        p1 += __shfl_xor(p1, 4, 64); p1 += __shfl_xor(p1, 2, 64); p1 += __shfl_xor(p1, 1, 64);
        const float w0 = __expf(p0), w1 = __expf(p1);
        s += w0 + w1;
#pragma unroll
        for (int j = 0; j < 8; ++j) acc[j] = fmaf(w0, f0[j], fmaf(w1, f1[j], acc[j]));
    }
    if (i < rp1) {
        const int s0 = csr_src[i];
        const ushx8 u0 = *reinterpret_cast<const ushx8*>(xl + (((size_t)(unsigned)s0) << 7) + il * 8);
        float f0[8], p0 = 0.f;
#pragma unroll
        for (int j = 0; j < 8; ++j) {
            f0[j] = bf2f((ush)u0[j]);
            const float v = f0[j] + xv[j];
            p0 = fmaf(av[j], fmaxf(v, 0.2f * v), p0);
        }
        p0 += __shfl_xor(p0, 4, 64); p0 += __shfl_xor(p0, 2, 64); p0 += __shfl_xor(p0, 1, 64);
        const float w0 = __expf(p0);
        s += w0;
#pragma unroll
        for (int j = 0; j < 8; ++j) acc[j] = fmaf(w0, f0[j], acc[j]);
    }
#pragma unroll
    for (int off = 16; off <= 32; off <<= 1) {
        s += __shfl_xor(s, off, 64);
#pragma unroll
        for (int j = 0; j < 8; ++j) acc[j] += __shfl_xor(acc[j], off, 64);
    }
    if (g == 0) {
        const float inv = 1.f / (s + 1e-16f);
        float bv[8];
        {
            const float4* bp = reinterpret_cast<const float4*>(bias + il * 8);
            const float4 b0 = bp[0], b1 = bp[1];
            bv[0]=b0.x; bv[1]=b0.y; bv[2]=b0.z; bv[3]=b0.w;
            bv[4]=b1.x; bv[5]=b1.y; bv[6]=b1.z; bv[7]=b1.w;
        }
        ushx8 hh, ll;
#pragma unroll
        for (int j = 0; j < 8; ++j) {
            const float o = fmaxf(fmaf(acc[j], inv, bv[j]), 0.f);
            const ush h = f2bf(o);
            hh[j] = h;
            ll[j] = f2bf(o - bf2f(h));
        }
        *reinterpret_cast<ushx8*>(h1hi + (size_t)d * 128 + il * 8) = hh;
        *reinterpret_cast<ushx8*>(h1lo + (size_t)d * 128 + il * 8) = ll;
    }
}

// ---------- fused per-dst softmax aggregation, H=1 (64 cols, xl bf16) ----------
// one wave per dst; 8 groups x 8 lanes x ushort8; scalar math.
__global__ __launch_bounds__(256) void gat_dst1_k(
    const ush* __restrict__ xl, const float* __restrict__ xr,
    const int* __restrict__ row_ptr, const int* __restrict__ csr_src,
    const int* __restrict__ order, const float* __restrict__ att,
    const float* __restrict__ bias, float* __restrict__ out, int n) {
    const int lane = threadIdx.x & 63;
    const int g = lane >> 3, il = lane & 7;
    const int w = (blockIdx.x * blockDim.x + threadIdx.x) >> 6;
    if (w >= n) return;
    const int d = order[w];

    float xv[8], av[8];
    {
        const float4* xp = reinterpret_cast<const float4*>(xr + (size_t)d * 64 + il * 8);
        const float4* ap = reinterpret_cast<const float4*>(att + il * 8);
        const float4 x0 = xp[0], x1 = xp[1], a0 = ap[0], a1 = ap[1];
        xv[0]=x0.x; xv[1]=x0.y; xv[2]=x0.z; xv[3]=x0.w;
        xv[4]=x1.x; xv[5]=x1.y; xv[6]=x1.z; xv[7]=x1.w;
        av[0]=a0.x; av[1]=a0.y; av[2]=a0.z; av[3]=a0.w;
        av[4]=a1.x; av[5]=a1.y; av[6]=a1.z; av[7]=a1.w;
    }
    const int rp0 = row_ptr[d], rp1 = row_ptr[d + 1];

    float s = 0.f;
    float acc[8] = {0.f, 0.f, 0.f, 0.f, 0.f, 0.f, 0.f, 0.f};
    int i = rp0 + g;
    for (; i + 8 < rp1; i += 16) {
        const int s0 = csr_src[i];
        const int s1 = csr_src[i + 8];
        const ushx8 u0 = *reinterpret_cast<const ushx8*>(xl + (((size_t)(unsigned)s0) << 6) + il * 8);
        const ushx8 u1 = *reinterpret_cast<const ushx8*>(xl + (((size_t)(unsigned)s1) << 6) + il * 8);
        float f0[8], f1[8], p0 = 0.f, p1 = 0.f;
#pragma unroll
        for (int j = 0; j < 8; ++j) {
            f0[j] = bf2f((ush)u0[j]);
            const float v = f0[j] + xv[j];
            p0 = fmaf(av[j], fmaxf(v, 0.2f * v), p0);
        }
#pragma unroll
        for (int j = 0; j < 8; ++j) {
            f1[j] = bf2f((ush)u1[j]);
            const float v = f1[j] + xv[j];
            p1 = fmaf(av[j], fmaxf(v, 0.2f * v), p1);
        }
        p0 += __shfl_xor(p0, 4, 64); p0 += __shfl_xor(p0, 2, 64); p0 += __shfl_xor(p0, 1, 64);
        p1 += __shfl_xor(p1, 4, 64); p1 += __shfl_xor(p1, 2, 64); p1 += __shfl_xor(p1, 1, 64);
        const float w0 = __expf(p0), w1 = __expf(p1);
        s += w0 + w1;
#pragma unroll
        for (int j = 0; j < 8; ++j) acc[j] = fmaf(w0, f0[j], fmaf(w1, f1[j], acc[j]));
    }
    if (i < rp1) {
        const int s0 = csr_src[i];
        const ushx8 u0 = *reinterpret_cast<const ushx8*>(xl + (((size_t)(unsigned)s0) << 6) + il * 8);
        float f0[8], p0 = 0.f;
#pragma unroll
        for (int j = 0; j < 8; ++j) {
            f0[j] = bf2f((ush)u0[j]);
            const float v = f0[j] + xv[j];
            p0 = fmaf(av[j], fmaxf(v, 0.2f * v), p0);
        }
        p0 += __shfl_xor(p0, 4, 64); p0 += __shfl_xor(p0, 2, 64); p0 += __shfl_xor(p0, 1, 64);
        const float w0 = __expf(p0);
        s += w0;
#pragma unroll
        for (int j = 0; j < 8; ++j) acc[j] = fmaf(w0, f0[j], acc[j]);
    }
#pragma unroll
    for (int off = 8; off <= 32; off <<= 1) {
        s += __shfl_xor(s, off, 64);
#pragma unroll
        for (int j = 0; j < 8; ++j) acc[j] += __shfl_xor(acc[j], off, 64);
    }
    if (g == 0) {
        const float inv = 1.f / (s + 1e-16f);
        float bv[8];
        {
            const float4* bp = reinterpret_cast<const float4*>(bias + il * 8);
            const float4 b0 = bp[0], b1 = bp[1];
            bv[0]=b0.x; bv[1]=b0.y; bv[2]=b0.z; bv[3]=b0.w;
            bv[4]=b1.x; bv[5]=b1.y; bv[6]=b1.z; bv[7]=b1.w;
        }
        float4 o0, o1;
        o0.x = fmaxf(fmaf(acc[0], inv, bv[0]), 0.f);
        o0.y = fmaxf(fmaf(acc[1], inv, bv[1]), 0.f);
        o0.z = fmaxf(fmaf(acc[2], inv, bv[2]), 0.f);
        o0.w = fmaxf(fmaf(acc[3], inv, bv[3]), 0.f);
        o1.x = fmaxf(fmaf(acc[4], inv, bv[4]), 0.f);
        o1.y = fmaxf(fmaf(acc[5], inv, bv[5]), 0.f);
        o1.z = fmaxf(fmaf(acc[6], inv, bv[6]), 0.f);
        o1.w = fmaxf(fmaf(acc[7], inv, bv[7]), 0.f);
        float4* op = reinterpret_cast<float4*>(out + (size_t)d * 64 + il * 8);
        op[0] = o0;
        op[1] = o1;
    }
}

extern "C" void kernel_launch(void* const* d_in, const int* in_sizes, int n_in,
                              void* d_out, int out_size, void* d_ws, size_t ws_size,
                              hipStream_t stream) {
    const float* x    = (const float*)d_in[0];
    const int*   ei   = (const int*)d_in[1];
    const float* Wl1  = (const float*)d_in[2];
    const float* Wr1  = (const float*)d_in[3];
    const float* att1 = (const float*)d_in[4];
    const float* b1   = (const float*)d_in[5];
    const float* Wl2  = (const float*)d_in[6];
    const float* Wr2  = (const float*)d_in[7];
    const float* att2 = (const float*)d_in[8];
    const float* b2   = (const float*)d_in[9];

    const int n    = in_sizes[0] / 128;   // 50000
    const int e0   = in_sizes[1] / 2;     // 800000
    const int etot = e0 + n;
    const int* srcs = ei;
    const int* dsts = ei + e0;

    float* ws = (float*)d_ws;
    ush*   h1hi = (ush*)ws;                        // n*128 ush
    ush*   h1lo = (ush*)(ws + (size_t)n * 64);     // n*128 ush
    ush*   xlbf = (ush*)(ws + (size_t)n * 128);    // n*128 ush
    float* xr   = ws + (size_t)n * 192;            // n*128 f32
    int* row_ptr = (int*)(ws + (size_t)n * 320);   // n+2
    int* ghist   = row_ptr + (n + 2);              // 512
    int* dbin    = ghist + 512;                    // 128
    int* dcur    = dbin + 128;                     // 128
    int* boff    = dcur + 128;                     // 512
    int* cur     = boff + 512;                     // 512
    int* order   = cur + 512;                      // n
    int* csr_src = order + n;                      // etot
    int* pairs   = csr_src + etot;                 // etot (packed)
    ush* wph     = (ush*)(pairs + etot);           // 96*512 ush
    ush* wpl     = wph + 96 * 512;                 // 96*512 ush

    const int NB  = (n + 127) / 128;               // 391 <= 512
    const int NDB = (n + 255) / 256;               // 196
    const int nblka = (etot + 2047) / 2048;

    // ---- CSR build via 2-level counting sort (+ fused degree hist) ----
    hipMemsetAsync(ghist, 0, 640 * sizeof(int), stream);  // ghist + dbin
    hist_k<<<256, 256, 0, stream>>>(dsts, ghist, e0, etot);
    scanb_k<<<1, 512, 0, stream>>>(ghist, boff, cur);
    semisort_k<<<nblka, 256, 0, stream>>>(srcs, dsts, cur, pairs, e0, etot);
    bucket_fill_k<<<NB, 256, 0, stream>>>(pairs, boff, row_ptr, csr_src, dbin, n, etot);
    deg_scan_k<<<1, 128, 0, stream>>>(dbin, dcur);
    deg_scatter_k<<<NDB, 256, 0, stream>>>(row_ptr, dcur, order, n);

    // ---- weight prep ----
    prep_w_k<<<96, 64, 0, stream>>>(Wl1, Wr1, Wl2, Wr2, wph, wpl);

    const int gx = (n + 63) / 64;

    // ---- layer 1 (H=2): xl bf16 [n,128], xr f32 [n,128] ----
    gemm1_k<<<gx, 256, 0, stream>>>(x, wph, wpl, wph + 32 * 512, wpl + 32 * 512,
                                    xlbf, xr, n);
    gat_dst2_k<<<(n + 3) / 4, 256, 0, stream>>>(xlbf, xr, row_ptr, csr_src, order,
                                                att1, b1, h1hi, h1lo, n);

    // ---- layer 2 (H=1): xl2 bf16 [n,64], xr2 f32 [n,64] ----
    gemm2_k<<<gx, 256, 0, stream>>>(h1hi, h1lo, wph + 64 * 512, wpl + 64 * 512,
                                    wph + 80 * 512, wpl + 80 * 512, xlbf, xr, n);
    gat_dst1_k<<<(n + 3) / 4, 256, 0, stream>>>(xlbf, xr, row_ptr, csr_src, order,
                                                att2, b2, (float*)d_out, n);
}